// Round 1
// baseline (29.783 us; speedup 1.0000x reference)
//
#include <hip/hip_runtime.h>

#define BB 16
#define TT 2048
#define DD 768

// ---------------------------------------------------------------------------
// Kernel A: per batch row, compute keep mask, block-wide inclusive scan,
// emit compaction source indices, lens, and the visible_padding_mask.
// One block (256 threads) per batch row; each thread owns 8 consecutive t.
// ---------------------------------------------------------------------------
__global__ void pm_scan_kernel(const int* __restrict__ nonvis,
                               const int* __restrict__ pad,
                               int* __restrict__ src_idx,
                               int* __restrict__ lens,
                               float* __restrict__ out_mask,
                               float* __restrict__ out_lens) {
    const int b = blockIdx.x;
    const int tid = threadIdx.x;          // 0..255
    const int base_t = tid * 8;

    const int* nv = nonvis + b * TT;
    const int* pd = pad + b * TT;

    int keep[8];
    int cnt = 0;
#pragma unroll
    for (int k = 0; k < 8; ++k) {
        const int t = base_t + k;
        const int kp = (nv[t] == 0) && (pd[t] == 0);
        keep[k] = kp;
        cnt += kp;
    }

    __shared__ int sdata[256];
    sdata[tid] = cnt;
    __syncthreads();

    // Hillis-Steele inclusive scan over 256 thread partials
    for (int off = 1; off < 256; off <<= 1) {
        int v = 0;
        if (tid >= off) v = sdata[tid - off];
        __syncthreads();
        sdata[tid] += v;
        __syncthreads();
    }

    const int incl = sdata[tid];
    const int total = sdata[255];   // broadcast read
    int pos = incl - cnt;           // exclusive prefix

    int* si = src_idx + b * TT;
#pragma unroll
    for (int k = 0; k < 8; ++k) {
        if (keep[k]) {
            si[pos] = base_t + k;
            ++pos;
        }
    }

    float* om = out_mask + b * TT;
#pragma unroll
    for (int k = 0; k < 8; ++k) {
        const int t = base_t + k;
        om[t] = (t >= total) ? 1.0f : 0.0f;
    }

    if (tid == 0) {
        lens[b] = total;
        out_lens[b] = (float)total;
    }
}

// ---------------------------------------------------------------------------
// Kernel B: one thread per float4 of the output [B,T,D]. Gathers the source
// row, adds inline-computed sinusoidal PE, zero-fills padded rows.
// ---------------------------------------------------------------------------
__global__ void pm_gather_kernel(const float* __restrict__ wav,
                                 const int* __restrict__ src_idx,
                                 const int* __restrict__ lens,
                                 float* __restrict__ out) {
    const int gid = blockIdx.x * blockDim.x + threadIdx.x;   // per float4
    const int D4 = DD / 4;                                   // 192
    const int d4 = gid % D4;
    const int row = gid / D4;
    const int j = row & (TT - 1);   // TT = 2048 = 2^11
    const int b = row >> 11;

    float4 v = make_float4(0.f, 0.f, 0.f, 0.f);
    if (j < lens[b]) {
        const int t = src_idx[b * TT + j];
        const float4 a =
            reinterpret_cast<const float4*>(wav + ((size_t)(b * TT + t)) * DD)[d4];
        const int d0 = d4 * 4;
        const float tf = (float)t;
        float pe[4];
#pragma unroll
        for (int k = 0; k < 4; ++k) {
            const int d = d0 + k;
            const int i = (d < DD / 2) ? d : (d - DD / 2);
            // 10000^(-2i/D) = exp(-ln(10000)*2/D * i); ln(10000)*2/768
            const float inv = __expf(-0.0239852613853510f * (float)i);
            const float ang = tf * inv;
            pe[k] = (d < DD / 2) ? __sinf(ang) : __cosf(ang);
        }
        v = make_float4(a.x + pe[0], a.y + pe[1], a.z + pe[2], a.w + pe[3]);
    }
    reinterpret_cast<float4*>(out)[gid] = v;
}

extern "C" void kernel_launch(void* const* d_in, const int* in_sizes, int n_in,
                              void* d_out, int out_size, void* d_ws, size_t ws_size,
                              hipStream_t stream) {
    const float* wav   = (const float*)d_in[0];
    const int* nonvis  = (const int*)d_in[1];
    const int* pad     = (const int*)d_in[2];

    float* out       = (float*)d_out;
    float* out_vis   = out;                              // B*T*D
    float* out_mask  = out + (size_t)BB * TT * DD;       // B*T
    float* out_lens  = out_mask + BB * TT;               // B

    int* src_idx = (int*)d_ws;          // B*T ints
    int* lens    = src_idx + BB * TT;   // B ints

    pm_scan_kernel<<<BB, 256, 0, stream>>>(nonvis, pad, src_idx, lens,
                                           out_mask, out_lens);

    const int n4 = BB * TT * DD / 4;    // 6,291,456 float4s
    pm_gather_kernel<<<n4 / 256, 256, 0, stream>>>(wav, src_idx, lens, out_vis);
}

// Round 3
// 28.645 us; speedup vs baseline: 1.0397x; 1.0397x over previous
//
#include <hip/hip_runtime.h>

#define BB 16
#define TT 2048
#define DD 768

typedef float f32x4 __attribute__((ext_vector_type(4)));

// ---------------------------------------------------------------------------
// Kernel A: per batch row, compute keep mask, wave-level inclusive scan
// (shuffle-based, 1 barrier), emit compaction source indices, lens, and the
// visible_padding_mask. One block (256 threads = 4 waves) per batch row;
// each thread owns 8 consecutive t.
// ---------------------------------------------------------------------------
__global__ void pm_scan_kernel(const int* __restrict__ nonvis,
                               const int* __restrict__ pad,
                               int* __restrict__ src_idx,
                               int* __restrict__ lens,
                               float* __restrict__ out_mask,
                               float* __restrict__ out_lens) {
    const int b = blockIdx.x;
    const int tid = threadIdx.x;          // 0..255
    const int base_t = tid * 8;
    const int lane = tid & 63;
    const int wid = tid >> 6;             // 0..3

    // Vector loads: 2x int4 per input mask
    const int4* nv4 = reinterpret_cast<const int4*>(nonvis + b * TT) + tid * 2;
    const int4* pd4 = reinterpret_cast<const int4*>(pad + b * TT) + tid * 2;
    const int4 nva = nv4[0], nvb = nv4[1];
    const int4 pda = pd4[0], pdb = pd4[1];

    int keep[8];
    keep[0] = (nva.x == 0) && (pda.x == 0);
    keep[1] = (nva.y == 0) && (pda.y == 0);
    keep[2] = (nva.z == 0) && (pda.z == 0);
    keep[3] = (nva.w == 0) && (pda.w == 0);
    keep[4] = (nvb.x == 0) && (pdb.x == 0);
    keep[5] = (nvb.y == 0) && (pdb.y == 0);
    keep[6] = (nvb.z == 0) && (pdb.z == 0);
    keep[7] = (nvb.w == 0) && (pdb.w == 0);

    int cnt = 0;
#pragma unroll
    for (int k = 0; k < 8; ++k) cnt += keep[k];

    // Wave-level inclusive scan of per-thread counts (6 shuffle rounds)
    int x = cnt;
#pragma unroll
    for (int off = 1; off < 64; off <<= 1) {
        const int v = __shfl_up(x, off);
        if (lane >= off) x += v;
    }

    // Combine the 4 wave totals through LDS (single barrier)
    __shared__ int wtot[4];
    if (lane == 63) wtot[wid] = x;
    __syncthreads();

    const int t0 = wtot[0], t1 = wtot[1], t2 = wtot[2], t3 = wtot[3];
    const int total = t0 + t1 + t2 + t3;
    int wbase = 0;
    if (wid > 0) wbase += t0;
    if (wid > 1) wbase += t1;
    if (wid > 2) wbase += t2;

    const int incl = wbase + x;
    int pos = incl - cnt;                 // exclusive prefix across the row

    int* si = src_idx + b * TT;
#pragma unroll
    for (int k = 0; k < 8; ++k) {
        if (keep[k]) {
            si[pos] = base_t + k;
            ++pos;
        }
    }

    // visible_padding_mask as floats, vectorized (2x float4 per thread)
    float m[8];
#pragma unroll
    for (int k = 0; k < 8; ++k) m[k] = (base_t + k >= total) ? 1.0f : 0.0f;
    float4* om4 = reinterpret_cast<float4*>(out_mask + b * TT) + tid * 2;
    om4[0] = make_float4(m[0], m[1], m[2], m[3]);
    om4[1] = make_float4(m[4], m[5], m[6], m[7]);

    if (tid == 0) {
        lens[b] = total;
        out_lens[b] = (float)total;
    }
}

// ---------------------------------------------------------------------------
// Kernel B: one thread per float4 of the output [B,T,D]. Gathers the source
// row, adds inline-computed sinusoidal PE, zero-fills padded rows.
// Nontemporal stores: output stream never re-read -> keep L2/L3 for wav.
// ---------------------------------------------------------------------------
__global__ void pm_gather_kernel(const float* __restrict__ wav,
                                 const int* __restrict__ src_idx,
                                 const int* __restrict__ lens,
                                 float* __restrict__ out) {
    const int gid = blockIdx.x * blockDim.x + threadIdx.x;   // per float4
    const int D4 = DD / 4;                                   // 192
    const int d4 = gid % D4;
    const int row = gid / D4;
    const int j = row & (TT - 1);   // TT = 2048 = 2^11
    const int b = row >> 11;

    f32x4 v = (f32x4)(0.f, 0.f, 0.f, 0.f);
    if (j < lens[b]) {
        const int t = src_idx[b * TT + j];
        const f32x4 a =
            reinterpret_cast<const f32x4*>(wav + ((size_t)(b * TT + t)) * DD)[d4];
        const int d0 = d4 * 4;
        const float tf = (float)t;
        float pe[4];
#pragma unroll
        for (int k = 0; k < 4; ++k) {
            const int d = d0 + k;
            const int i = (d < DD / 2) ? d : (d - DD / 2);
            // 10000^(-2i/D) = exp(-ln(10000)*2/D * i); ln(10000)*2/768
            const float inv = __expf(-0.0239852613853510f * (float)i);
            const float ang = tf * inv;
            pe[k] = (d < DD / 2) ? __sinf(ang) : __cosf(ang);
        }
        v = (f32x4)(a.x + pe[0], a.y + pe[1], a.z + pe[2], a.w + pe[3]);
    }
    __builtin_nontemporal_store(v, reinterpret_cast<f32x4*>(out) + gid);
}

extern "C" void kernel_launch(void* const* d_in, const int* in_sizes, int n_in,
                              void* d_out, int out_size, void* d_ws, size_t ws_size,
                              hipStream_t stream) {
    const float* wav   = (const float*)d_in[0];
    const int* nonvis  = (const int*)d_in[1];
    const int* pad     = (const int*)d_in[2];

    float* out       = (float*)d_out;
    float* out_vis   = out;                              // B*T*D
    float* out_mask  = out + (size_t)BB * TT * DD;       // B*T
    float* out_lens  = out_mask + BB * TT;               // B

    int* src_idx = (int*)d_ws;          // B*T ints
    int* lens    = src_idx + BB * TT;   // B ints

    pm_scan_kernel<<<BB, 256, 0, stream>>>(nonvis, pad, src_idx, lens,
                                           out_mask, out_lens);

    const int n4 = BB * TT * DD / 4;    // 6,291,456 float4s
    pm_gather_kernel<<<n4 / 256, 256, 0, stream>>>(wav, src_idx, lens, out_vis);
}

// Round 4
// 28.541 us; speedup vs baseline: 1.0435x; 1.0037x over previous
//
#include <hip/hip_runtime.h>

#define BB 16
#define TT 2048
#define DD 768

typedef float f32x4 __attribute__((ext_vector_type(4)));

// ---------------------------------------------------------------------------
// Kernel A: per batch row, compute keep mask, wave-level inclusive scan
// (shuffle-based, 1 barrier), emit compaction source indices, lens, and the
// visible_padding_mask. One block (256 threads = 4 waves) per batch row;
// each thread owns 8 consecutive t.
// ---------------------------------------------------------------------------
__global__ void pm_scan_kernel(const int* __restrict__ nonvis,
                               const int* __restrict__ pad,
                               int* __restrict__ src_idx,
                               int* __restrict__ lens,
                               float* __restrict__ out_mask,
                               float* __restrict__ out_lens) {
    const int b = blockIdx.x;
    const int tid = threadIdx.x;          // 0..255
    const int base_t = tid * 8;
    const int lane = tid & 63;
    const int wid = tid >> 6;             // 0..3

    // Vector loads: 2x int4 per input mask
    const int4* nv4 = reinterpret_cast<const int4*>(nonvis + b * TT) + tid * 2;
    const int4* pd4 = reinterpret_cast<const int4*>(pad + b * TT) + tid * 2;
    const int4 nva = nv4[0], nvb = nv4[1];
    const int4 pda = pd4[0], pdb = pd4[1];

    int keep[8];
    keep[0] = (nva.x == 0) && (pda.x == 0);
    keep[1] = (nva.y == 0) && (pda.y == 0);
    keep[2] = (nva.z == 0) && (pda.z == 0);
    keep[3] = (nva.w == 0) && (pda.w == 0);
    keep[4] = (nvb.x == 0) && (pdb.x == 0);
    keep[5] = (nvb.y == 0) && (pdb.y == 0);
    keep[6] = (nvb.z == 0) && (pdb.z == 0);
    keep[7] = (nvb.w == 0) && (pdb.w == 0);

    int cnt = 0;
#pragma unroll
    for (int k = 0; k < 8; ++k) cnt += keep[k];

    // Wave-level inclusive scan of per-thread counts (6 shuffle rounds)
    int x = cnt;
#pragma unroll
    for (int off = 1; off < 64; off <<= 1) {
        const int v = __shfl_up(x, off);
        if (lane >= off) x += v;
    }

    // Combine the 4 wave totals through LDS (single barrier)
    __shared__ int wtot[4];
    if (lane == 63) wtot[wid] = x;
    __syncthreads();

    const int t0 = wtot[0], t1 = wtot[1], t2 = wtot[2], t3 = wtot[3];
    const int total = t0 + t1 + t2 + t3;
    int wbase = 0;
    if (wid > 0) wbase += t0;
    if (wid > 1) wbase += t1;
    if (wid > 2) wbase += t2;

    const int incl = wbase + x;
    int pos = incl - cnt;                 // exclusive prefix across the row

    int* si = src_idx + b * TT;
#pragma unroll
    for (int k = 0; k < 8; ++k) {
        if (keep[k]) {
            si[pos] = base_t + k;
            ++pos;
        }
    }

    // visible_padding_mask as floats, vectorized (2x float4 per thread)
    float m[8];
#pragma unroll
    for (int k = 0; k < 8; ++k) m[k] = (base_t + k >= total) ? 1.0f : 0.0f;
    float4* om4 = reinterpret_cast<float4*>(out_mask + b * TT) + tid * 2;
    om4[0] = make_float4(m[0], m[1], m[2], m[3]);
    om4[1] = make_float4(m[4], m[5], m[6], m[7]);

    if (tid == 0) {
        lens[b] = total;
        out_lens[b] = (float)total;
    }
}

// ---------------------------------------------------------------------------
// Kernel B: one WAVE per output row [b][j]. 192 float4s per row = 3 per lane.
// Branch on j < lens[b] is wave-uniform; lens/src_idx/index math amortized.
// Gathers the source row, adds inline sinusoidal PE, zero-fills padded rows.
// Nontemporal stores: output never re-read -> keep L2/L3 for wav.
// ---------------------------------------------------------------------------
__global__ void pm_gather_kernel(const float* __restrict__ wav,
                                 const int* __restrict__ src_idx,
                                 const int* __restrict__ lens,
                                 float* __restrict__ out) {
    const int lane = threadIdx.x & 63;
    const int wid  = threadIdx.x >> 6;            // 0..3
    const int row  = blockIdx.x * 4 + wid;        // 0..B*T-1
    const int j = row & (TT - 1);                 // TT = 2^11
    const int b = row >> 11;

    f32x4* orow = reinterpret_cast<f32x4*>(out + (size_t)row * DD);

    if (j < lens[b]) {
        const int t = src_idx[b * TT + j];
        const f32x4* arow =
            reinterpret_cast<const f32x4*>(wav + ((size_t)(b * TT + t)) * DD);
        const float tf = (float)t;
#pragma unroll
        for (int s = 0; s < 3; ++s) {
            const int d4 = lane + s * 64;
            const f32x4 a = arow[d4];
            const int d0 = d4 * 4;
            f32x4 v;
#pragma unroll
            for (int k = 0; k < 4; ++k) {
                const int d = d0 + k;
                const int i = (d < DD / 2) ? d : (d - DD / 2);
                // 10000^(-2i/D) = exp(-ln(10000)*2/D * i); ln(10000)*2/768
                const float inv = __expf(-0.0239852613853510f * (float)i);
                const float ang = tf * inv;
                const float pe = (d < DD / 2) ? __sinf(ang) : __cosf(ang);
                v[k] = a[k] + pe;
            }
            __builtin_nontemporal_store(v, orow + d4);
        }
    } else {
        const f32x4 z = {0.f, 0.f, 0.f, 0.f};
#pragma unroll
        for (int s = 0; s < 3; ++s)
            __builtin_nontemporal_store(z, orow + lane + s * 64);
    }
}

extern "C" void kernel_launch(void* const* d_in, const int* in_sizes, int n_in,
                              void* d_out, int out_size, void* d_ws, size_t ws_size,
                              hipStream_t stream) {
    const float* wav   = (const float*)d_in[0];
    const int* nonvis  = (const int*)d_in[1];
    const int* pad     = (const int*)d_in[2];

    float* out       = (float*)d_out;
    float* out_vis   = out;                              // B*T*D
    float* out_mask  = out + (size_t)BB * TT * DD;       // B*T
    float* out_lens  = out_mask + BB * TT;               // B

    int* src_idx = (int*)d_ws;          // B*T ints
    int* lens    = src_idx + BB * TT;   // B ints

    pm_scan_kernel<<<BB, 256, 0, stream>>>(nonvis, pad, src_idx, lens,
                                           out_mask, out_lens);

    // One wave per output row; 4 rows per 256-thread block.
    pm_gather_kernel<<<BB * TT / 4, 256, 0, stream>>>(wav, src_idx, lens, out_vis);
}

// Round 5
// 25.762 us; speedup vs baseline: 1.1561x; 1.1079x over previous
//
#include <hip/hip_runtime.h>

#define BB 16
#define TT 2048
#define DD 768

typedef float f32x4 __attribute__((ext_vector_type(4)));

// ---------------------------------------------------------------------------
// Fused kernel: one block per 16 output rows of one batch. Each block
// redundantly re-reads its batch's masks (L2-resident, 16 KB) and recomputes
// the block-wide prefix scan (shuffle-based), selects the 16 source indices
// for its output rows into LDS, then gathers those rows with inline PE and
// zero-fills padded rows. No inter-kernel dependency, no workspace.
//
// Grid: BB * TT / 16 = 2048 blocks x 256 threads (4 waves).
// Per block: scan thread t owns 8 consecutive positions; gather wave w owns
// rows j0+w*4..+3, 3 float4/lane per row.
// ---------------------------------------------------------------------------
__global__ void pm_fused_kernel(const int* __restrict__ nonvis,
                                const int* __restrict__ pad,
                                const float* __restrict__ wav,
                                float* __restrict__ out_vis,
                                float* __restrict__ out_mask,
                                float* __restrict__ out_lens) {
    const int blk = blockIdx.x;            // 0..2047
    const int b = blk >> 7;                // blk / 128
    const int j0 = (blk & 127) << 4;       // 16 rows per block
    const int tid = threadIdx.x;           // 0..255
    const int base_t = tid * 8;
    const int lane = tid & 63;
    const int wid = tid >> 6;              // 0..3

    // ---- scan phase (redundant per block; masks are L2-resident) ----
    const int4* nv4 = reinterpret_cast<const int4*>(nonvis + b * TT) + tid * 2;
    const int4* pd4 = reinterpret_cast<const int4*>(pad + b * TT) + tid * 2;
    const int4 nva = nv4[0], nvb = nv4[1];
    const int4 pda = pd4[0], pdb = pd4[1];

    int keep[8];
    keep[0] = (nva.x == 0) && (pda.x == 0);
    keep[1] = (nva.y == 0) && (pda.y == 0);
    keep[2] = (nva.z == 0) && (pda.z == 0);
    keep[3] = (nva.w == 0) && (pda.w == 0);
    keep[4] = (nvb.x == 0) && (pdb.x == 0);
    keep[5] = (nvb.y == 0) && (pdb.y == 0);
    keep[6] = (nvb.z == 0) && (pdb.z == 0);
    keep[7] = (nvb.w == 0) && (pdb.w == 0);

    int cnt = 0;
#pragma unroll
    for (int k = 0; k < 8; ++k) cnt += keep[k];

    // wave-level inclusive scan (6 shuffle rounds)
    int x = cnt;
#pragma unroll
    for (int off = 1; off < 64; off <<= 1) {
        const int v = __shfl_up(x, off);
        if (lane >= off) x += v;
    }

    __shared__ int wtot[4];
    __shared__ int s_src[16];
    if (lane == 63) wtot[wid] = x;
    __syncthreads();

    const int t0 = wtot[0], t1 = wtot[1], t2 = wtot[2], t3 = wtot[3];
    const int total = t0 + t1 + t2 + t3;
    int wbase = 0;
    if (wid > 0) wbase += t0;
    if (wid > 1) wbase += t1;
    if (wid > 2) wbase += t2;

    // exclusive prefix of this thread's first element
    int p = wbase + x - cnt;

    // select the source t for output rows [j0, j0+16) into LDS
#pragma unroll
    for (int k = 0; k < 8; ++k) {
        if (keep[k]) {
            const int r = p - j0;
            if ((unsigned)r < 16u) s_src[r] = base_t + k;
            ++p;
        }
    }
    __syncthreads();

    // ---- small outputs ----
    if (tid < 16)
        out_mask[b * TT + j0 + tid] = (j0 + tid >= total) ? 1.0f : 0.0f;
    if ((blk & 127) == 0 && tid == 0)
        out_lens[b] = (float)total;

    // ---- gather phase: wave wid handles rows j0 + wid*4 .. +3 ----
    // per-lane d positions are fixed: d4 = lane + s*64; hoist inv(d) factors
    float invf[3];
    bool is_sin[3];
#pragma unroll
    for (int s = 0; s < 3; ++s) {
        // representative: all 4 elems of a float4 share the sin/cos half
        // (d0..d0+3 all < 384 or all >= 384 since 384 % 4 == 0)
        const int d0 = (lane + s * 64) * 4;
        is_sin[s] = (d0 < DD / 2);
        (void)invf;
    }

#pragma unroll
    for (int q = 0; q < 4; ++q) {
        const int r = wid * 4 + q;
        const int j = j0 + r;
        f32x4* orow = reinterpret_cast<f32x4*>(out_vis + ((size_t)(b * TT + j)) * DD);

        if (j < total) {
            const int t = s_src[r];
            const f32x4* arow =
                reinterpret_cast<const f32x4*>(wav + ((size_t)(b * TT + t)) * DD);
            const float tf = (float)t;
#pragma unroll
            for (int s = 0; s < 3; ++s) {
                const int d4 = lane + s * 64;
                const f32x4 a = arow[d4];
                const int d0 = d4 * 4;
                f32x4 v;
#pragma unroll
                for (int k = 0; k < 4; ++k) {
                    const int d = d0 + k;
                    const int i = is_sin[s] ? d : (d - DD / 2);
                    // 10000^(-2i/D) = exp(-ln(10000)*2/D * i)
                    const float inv = __expf(-0.0239852613853510f * (float)i);
                    const float ang = tf * inv;
                    const float pe = is_sin[s] ? __sinf(ang) : __cosf(ang);
                    v[k] = a[k] + pe;
                }
                __builtin_nontemporal_store(v, orow + d4);
            }
        } else {
            const f32x4 z = {0.f, 0.f, 0.f, 0.f};
#pragma unroll
            for (int s = 0; s < 3; ++s)
                __builtin_nontemporal_store(z, orow + lane + s * 64);
        }
    }
}

extern "C" void kernel_launch(void* const* d_in, const int* in_sizes, int n_in,
                              void* d_out, int out_size, void* d_ws, size_t ws_size,
                              hipStream_t stream) {
    const float* wav   = (const float*)d_in[0];
    const int* nonvis  = (const int*)d_in[1];
    const int* pad     = (const int*)d_in[2];

    float* out       = (float*)d_out;
    float* out_vis   = out;                              // B*T*D
    float* out_mask  = out + (size_t)BB * TT * DD;       // B*T
    float* out_lens  = out_mask + BB * TT;               // B

    pm_fused_kernel<<<BB * TT / 16, 256, 0, stream>>>(nonvis, pad, wav,
                                                      out_vis, out_mask, out_lens);
}

// Round 6
// 24.960 us; speedup vs baseline: 1.1932x; 1.0321x over previous
//
#include <hip/hip_runtime.h>

#define BB 16
#define TT 2048
#define DD 768

typedef float f32x4 __attribute__((ext_vector_type(4)));

// ---------------------------------------------------------------------------
// Fused kernel: one block per 16 output rows of one batch. Each block
// redundantly re-reads its batch's masks (L2-resident, 16 KB) and recomputes
// the block-wide prefix scan (shuffle-based), selects the 16 source indices
// for its output rows into LDS, then gathers those rows with inline PE and
// zero-fills padded rows.
//
// R6 changes: (1) regular stores for out_vis (A/B vs nontemporal — fills
// prove regular stores sustain 6.9 TB/s); (2) per-lane exp factors hoisted
// out of the row loop explicitly.
// ---------------------------------------------------------------------------
__global__ void pm_fused_kernel(const int* __restrict__ nonvis,
                                const int* __restrict__ pad,
                                const float* __restrict__ wav,
                                float* __restrict__ out_vis,
                                float* __restrict__ out_mask,
                                float* __restrict__ out_lens) {
    const int blk = blockIdx.x;            // 0..2047
    const int b = blk >> 7;                // blk / 128
    const int j0 = (blk & 127) << 4;       // 16 rows per block
    const int tid = threadIdx.x;           // 0..255
    const int base_t = tid * 8;
    const int lane = tid & 63;
    const int wid = tid >> 6;              // 0..3

    // ---- scan phase (redundant per block; masks are L2-resident) ----
    const int4* nv4 = reinterpret_cast<const int4*>(nonvis + b * TT) + tid * 2;
    const int4* pd4 = reinterpret_cast<const int4*>(pad + b * TT) + tid * 2;
    const int4 nva = nv4[0], nvb = nv4[1];
    const int4 pda = pd4[0], pdb = pd4[1];

    int keep[8];
    keep[0] = (nva.x == 0) && (pda.x == 0);
    keep[1] = (nva.y == 0) && (pda.y == 0);
    keep[2] = (nva.z == 0) && (pda.z == 0);
    keep[3] = (nva.w == 0) && (pda.w == 0);
    keep[4] = (nvb.x == 0) && (pdb.x == 0);
    keep[5] = (nvb.y == 0) && (pdb.y == 0);
    keep[6] = (nvb.z == 0) && (pdb.z == 0);
    keep[7] = (nvb.w == 0) && (pdb.w == 0);

    int cnt = 0;
#pragma unroll
    for (int k = 0; k < 8; ++k) cnt += keep[k];

    // wave-level inclusive scan (6 shuffle rounds)
    int x = cnt;
#pragma unroll
    for (int off = 1; off < 64; off <<= 1) {
        const int v = __shfl_up(x, off);
        if (lane >= off) x += v;
    }

    __shared__ int wtot[4];
    __shared__ int s_src[16];
    if (lane == 63) wtot[wid] = x;
    __syncthreads();

    const int t0 = wtot[0], t1 = wtot[1], t2 = wtot[2], t3 = wtot[3];
    const int total = t0 + t1 + t2 + t3;
    int wbase = 0;
    if (wid > 0) wbase += t0;
    if (wid > 1) wbase += t1;
    if (wid > 2) wbase += t2;

    // exclusive prefix of this thread's first element
    int p = wbase + x - cnt;

    // select the source t for output rows [j0, j0+16) into LDS
#pragma unroll
    for (int k = 0; k < 8; ++k) {
        if (keep[k]) {
            const int r = p - j0;
            if ((unsigned)r < 16u) s_src[r] = base_t + k;
            ++p;
        }
    }
    __syncthreads();

    // ---- small outputs ----
    if (tid < 16)
        out_mask[b * TT + j0 + tid] = (j0 + tid >= total) ? 1.0f : 0.0f;
    if ((blk & 127) == 0 && tid == 0)
        out_lens[b] = (float)total;

    // ---- hoisted per-lane PE factors (independent of output row) ----
    // d4 = lane + s*64; d = d4*4 + k; i = d (sin half) or d-384 (cos half)
    float inv[3][4];
    bool is_sin[3];
#pragma unroll
    for (int s = 0; s < 3; ++s) {
        const int d0 = (lane + s * 64) * 4;
        is_sin[s] = (d0 < DD / 2);
#pragma unroll
        for (int k = 0; k < 4; ++k) {
            const int d = d0 + k;
            const int i = is_sin[s] ? d : (d - DD / 2);
            // 10000^(-2i/D) = exp(-ln(10000)*2/D * i); ln(10000)*2/768
            inv[s][k] = __expf(-0.0239852613853510f * (float)i);
        }
    }

    // ---- gather phase: wave wid handles rows j0 + wid*4 .. +3 ----
#pragma unroll
    for (int q = 0; q < 4; ++q) {
        const int r = wid * 4 + q;
        const int j = j0 + r;
        f32x4* orow = reinterpret_cast<f32x4*>(out_vis + ((size_t)(b * TT + j)) * DD);

        if (j < total) {
            const int t = s_src[r];
            const f32x4* arow =
                reinterpret_cast<const f32x4*>(wav + ((size_t)(b * TT + t)) * DD);
            const float tf = (float)t;
#pragma unroll
            for (int s = 0; s < 3; ++s) {
                const int d4 = lane + s * 64;
                const f32x4 a = arow[d4];
                f32x4 v;
#pragma unroll
                for (int k = 0; k < 4; ++k) {
                    const float ang = tf * inv[s][k];
                    const float pe = is_sin[s] ? __sinf(ang) : __cosf(ang);
                    v[k] = a[k] + pe;
                }
                orow[d4] = v;
            }
        } else {
            const f32x4 z = {0.f, 0.f, 0.f, 0.f};
#pragma unroll
            for (int s = 0; s < 3; ++s)
                orow[lane + s * 64] = z;
        }
    }
}

extern "C" void kernel_launch(void* const* d_in, const int* in_sizes, int n_in,
                              void* d_out, int out_size, void* d_ws, size_t ws_size,
                              hipStream_t stream) {
    const float* wav   = (const float*)d_in[0];
    const int* nonvis  = (const int*)d_in[1];
    const int* pad     = (const int*)d_in[2];

    float* out       = (float*)d_out;
    float* out_vis   = out;                              // B*T*D
    float* out_mask  = out + (size_t)BB * TT * DD;       // B*T
    float* out_lens  = out_mask + BB * TT;               // B

    pm_fused_kernel<<<BB * TT / 16, 256, 0, stream>>>(nonvis, pad, wav,
                                                      out_vis, out_mask, out_lens);
}